// Round 1
// baseline (218.206 us; speedup 1.0000x reference)
//
#include <hip/hip_runtime.h>

namespace {

constexpr int   IMG = 512;
constexpr int   TS  = 64;
constexpr float THRESHOLD = 50.0f / 255.0f;

// jax.image.resize 'linear', 256 -> 512, half-pixel centers + boundary renorm:
// out[0]=in[0]; out[2k]=0.25*in[k-1]+0.75*in[k]; out[2k+1]=0.75*in[k]+0.25*in[k+1]; out[511]=in[255]
__device__ __forceinline__ void resize_taps(int g, int& i0, int& i1, float& w0, float& w1) {
  int k = g >> 1;
  if ((g & 1) == 0) {
    i0 = k - 1; i1 = k; w0 = 0.25f; w1 = 0.75f;
    if (g == 0) { i0 = 0; w0 = 0.0f; w1 = 1.0f; }
  } else {
    i0 = k; i1 = k + 1; w0 = 0.75f; w1 = 0.25f;
    if (i1 > 255) { i1 = 255; w0 = 1.0f; w1 = 0.0f; }
  }
}

__global__ void zero_acc_kernel(double* __restrict__ acc) {
  if (threadIdx.x < 5) acc[threadIdx.x] = 0.0;
}

__global__ __launch_bounds__(256) void n2n_wavelet_kernel(
    const float* __restrict__ noisy,
    const float* __restrict__ weight,
    double* __restrict__ acc) {
  // LDS: odd leading strides -> conflict-free
  __shared__ float sN[72][73];     // clamped noisy window
  __shared__ float sG1[66][67];    // g1 tile with conv halo (reused for LL pyramids)
  __shared__ float sOut[64][65];   // clipped conv output tile
  __shared__ float sRed[4][8];

  const int t  = threadIdx.x;
  const int tx = blockIdx.x;
  const int ty = blockIdx.y;
  const int b  = blockIdx.z;

  const float* img = noisy + (size_t)b * IMG * IMG;
  const int nY0 = ty * TS - 4;
  const int nX0 = tx * TS - 4;

  float wk[9];
#pragma unroll
  for (int i = 0; i < 9; ++i) wk[i] = weight[i];

  // ---- Phase A: stage 72x72 noisy window (clamped; clamped cells never read) ----
  for (int idx = t; idx < 72 * 72; idx += 256) {
    int r = idx / 72;
    int c = idx - r * 72;
    int gr = nY0 + r; gr = gr < 0 ? 0 : (gr > IMG - 1 ? IMG - 1 : gr);
    int gc = nX0 + c; gc = gc < 0 ? 0 : (gc > IMG - 1 ? IMG - 1 : gc);
    sN[r][c] = img[gr * IMG + gc];
  }
  __syncthreads();

  // ---- Phase B: g1 tile 66x66 (halo 1 for conv; zero outside image = SAME pad) ----
  // g1 from p0 = noisy[0::2, 0::2]; p0(i,j) at sN[2i - nY0][2j - nX0]
  for (int idx = t; idx < 66 * 66; idx += 256) {
    int ly = idx / 66;
    int lx = idx - ly * 66;
    int gy = ty * TS - 1 + ly;
    int gx = tx * TS - 1 + lx;
    float v = 0.0f;
    if ((unsigned)gy < (unsigned)IMG && (unsigned)gx < (unsigned)IMG) {
      int i0, i1, j0, j1; float wy0, wy1, wx0, wx1;
      resize_taps(gy, i0, i1, wy0, wy1);
      resize_taps(gx, j0, j1, wx0, wx1);
      int r0 = 2 * i0 - nY0, r1 = 2 * i1 - nY0;
      int c0 = 2 * j0 - nX0, c1 = 2 * j1 - nX0;
      v = wy0 * (wx0 * sN[r0][c0] + wx1 * sN[r0][c1])
        + wy1 * (wx0 * sN[r1][c0] + wx1 * sN[r1][c1]);
    }
    sG1[ly][lx] = v;
  }
  __syncthreads();

  // ---- Phase C: out = clip(conv3x3(g1),0,1); accumulate rec/reg ----
  // g2 from p3 = noisy[1::2, 1::2]; p3(i,j) at sN[2i+1 - nY0][2j+1 - nX0]
  float rec_acc = 0.0f, reg_acc = 0.0f;
  for (int idx = t; idx < TS * TS; idx += 256) {
    int ly = idx >> 6;
    int lx = idx & 63;
    float o =
        sG1[ly    ][lx    ] * wk[0] + sG1[ly    ][lx + 1] * wk[1] + sG1[ly    ][lx + 2] * wk[2]
      + sG1[ly + 1][lx    ] * wk[3] + sG1[ly + 1][lx + 1] * wk[4] + sG1[ly + 1][lx + 2] * wk[5]
      + sG1[ly + 2][lx    ] * wk[6] + sG1[ly + 2][lx + 1] * wk[7] + sG1[ly + 2][lx + 2] * wk[8];
    o = o < 0.0f ? 0.0f : (o > 1.0f ? 1.0f : o);
    sOut[ly][lx] = o;

    int gy = ty * TS + ly;
    int gx = tx * TS + lx;
    int i0, i1, j0, j1; float wy0, wy1, wx0, wx1;
    resize_taps(gy, i0, i1, wy0, wy1);
    resize_taps(gx, j0, j1, wx0, wx1);
    int r0 = 2 * i0 + 1 - nY0, r1 = 2 * i1 + 1 - nY0;
    int c0 = 2 * j0 + 1 - nX0, c1 = 2 * j1 + 1 - nX0;
    float g2 = wy0 * (wx0 * sN[r0][c0] + wx1 * sN[r0][c1])
             + wy1 * (wx0 * sN[r1][c0] + wx1 * sN[r1][c1]);
    float g1c = sG1[ly + 1][lx + 1];
    float dr = o - g2;  rec_acc += dr * dr;
    float dg = o - g1c; reg_acc += dg * dg;
  }
  __syncthreads();

  // ---- Phase D: 3-level Haar on sOut; LL pyramids reuse sG1 storage ----
  float w1_acc = 0.0f, w2_acc = 0.0f, w3_acc = 0.0f;
  float* sLL1 = &sG1[0][0];            // 32 x 33
  float* sLL2 = &sG1[0][0] + 32 * 33;  // 16 x 17
  const float thr1 = THRESHOLD * 0.25f;  // level j=1: level_idx 3 -> THR/4
  const float thr2 = THRESHOLD * 0.5f;   // level j=2: THR/2
  const float thr3 = THRESHOLD;          // level j=3: THR

  for (int idx = t; idx < 32 * 32; idx += 256) {
    int i = idx >> 5, j = idx & 31;
    float a = sOut[2 * i][2 * j],     bq = sOut[2 * i][2 * j + 1];
    float c = sOut[2 * i + 1][2 * j], d  = sOut[2 * i + 1][2 * j + 1];
    sLL1[i * 33 + j] = (a + bq + c + d) * 0.5f;
    float lh = (a - bq + c - d) * 0.5f;
    float hl = (a + bq - c - d) * 0.5f;
    float hh = (a - bq - c + d) * 0.5f;
    w1_acc += fminf(fabsf(lh), thr1) + fminf(fabsf(hl), thr1) + fminf(fabsf(hh), thr1);
  }
  __syncthreads();

  {  // level 2: 16x16 = exactly 256 items
    int i = t >> 4, j = t & 15;
    float a = sLL1[(2 * i) * 33 + 2 * j],     bq = sLL1[(2 * i) * 33 + 2 * j + 1];
    float c = sLL1[(2 * i + 1) * 33 + 2 * j], d  = sLL1[(2 * i + 1) * 33 + 2 * j + 1];
    sLL2[i * 17 + j] = (a + bq + c + d) * 0.5f;
    float lh = (a - bq + c - d) * 0.5f;
    float hl = (a + bq - c - d) * 0.5f;
    float hh = (a - bq - c + d) * 0.5f;
    w2_acc += fminf(fabsf(lh), thr2) + fminf(fabsf(hl), thr2) + fminf(fabsf(hh), thr2);
  }
  __syncthreads();

  if (t < 64) {  // level 3: 8x8
    int i = t >> 3, j = t & 7;
    float a = sLL2[(2 * i) * 17 + 2 * j],     bq = sLL2[(2 * i) * 17 + 2 * j + 1];
    float c = sLL2[(2 * i + 1) * 17 + 2 * j], d  = sLL2[(2 * i + 1) * 17 + 2 * j + 1];
    float lh = (a - bq + c - d) * 0.5f;
    float hl = (a + bq - c - d) * 0.5f;
    float hh = (a - bq - c + d) * 0.5f;
    w3_acc += fminf(fabsf(lh), thr3) + fminf(fabsf(hl), thr3) + fminf(fabsf(hh), thr3);
  }

  // ---- Block reduce 5 sums -> double atomics ----
  float vals[5] = {rec_acc, reg_acc, w1_acc, w2_acc, w3_acc};
#pragma unroll
  for (int v = 0; v < 5; ++v) {
    float x = vals[v];
#pragma unroll
    for (int off = 32; off > 0; off >>= 1) x += __shfl_down(x, off);
    vals[v] = x;
  }
  int wave = t >> 6, lane = t & 63;
  if (lane == 0) {
#pragma unroll
    for (int v = 0; v < 5; ++v) sRed[wave][v] = vals[v];
  }
  __syncthreads();
  if (t == 0) {
#pragma unroll
    for (int v = 0; v < 5; ++v) {
      double s = (double)sRed[0][v] + (double)sRed[1][v] + (double)sRed[2][v] + (double)sRed[3][v];
      atomicAdd(&acc[v], s);
    }
  }
}

__global__ void finalize_kernel(const double* __restrict__ acc, float* __restrict__ out) {
  const double N  = 32.0 * 512.0 * 512.0;
  const double N1 = 32.0 * 256.0 * 256.0;
  const double N2 = 32.0 * 128.0 * 128.0;
  const double N3 = 32.0 * 64.0 * 64.0;
  double rec  = acc[0] / N;
  double reg  = acc[1] / N;
  double lvl1 = acc[2] / (3.0 * N1);
  double lvl2 = acc[3] / (3.0 * N2);
  double lvl3 = acc[4] / (3.0 * N3);
  // total = rec + GAMMA*reg + 0.05 * ( (1/3)*lvl1 + (1/2)*lvl2 + 1*lvl3 )
  double total = rec + 2.0 * reg + 0.05 * (lvl1 / 3.0 + lvl2 / 2.0 + lvl3);
  out[0] = (float)total;
}

}  // namespace

extern "C" void kernel_launch(void* const* d_in, const int* in_sizes, int n_in,
                              void* d_out, int out_size, void* d_ws, size_t ws_size,
                              hipStream_t stream) {
  const float* noisy  = (const float*)d_in[0];
  const float* weight = (const float*)d_in[1];
  double* acc = (double*)d_ws;
  float* out  = (float*)d_out;

  hipLaunchKernelGGL(zero_acc_kernel, dim3(1), dim3(64), 0, stream, acc);
  dim3 grid(IMG / TS, IMG / TS, 32);
  hipLaunchKernelGGL(n2n_wavelet_kernel, grid, dim3(256), 0, stream, noisy, weight, acc);
  hipLaunchKernelGGL(finalize_kernel, dim3(1), dim3(1), 0, stream, acc, out);
}